// Round 7
// baseline (425.304 us; speedup 1.0000x reference)
//
#include <hip/hip_runtime.h>
#include <math.h>

#define N_NODES 50000
#define E_EDGES 400000
#define NPRE_BLOCKS 6250          // N_NODES/8
#define NHIST_BLOCKS 1563         // ceil(E/256)

typedef _Float16 f16x2 __attribute__((ext_vector_type(2)));
typedef _Float16 f16x4 __attribute__((ext_vector_type(4)));
typedef _Float16 f16x8 __attribute__((ext_vector_type(8)));
typedef float    f32x4 __attribute__((ext_vector_type(4)));

static constexpr float S_IN      = 0.17677669529663687f;   // 1/sqrt(32)
static constexpr float S_MID     = 0.125f;                 // 1/sqrt(64)
static constexpr float S_SE      = 0.08838834764831843f;   // 1/sqrt(128)
static constexpr float INV_NN    = 0.35355339059327373f;   // 1/sqrt(8)
static constexpr float INV_SQRT3 = 0.5773502691896258f;
static constexpr float FC1_S     = 0.25f;                  // 1/sqrt(16)
static constexpr float FC2_S     = 0.125f;                 // 1/sqrt(64)

// ws fp16 weight image layout (halfs): W2T[c][72] @0 (9216) | W1T[j][40] @9216
// (2560, k>=16 zero) | BT[16][264] @11776 (4224). Total 16000 halfs = 32 KB.
#define WSW_W2T 0
#define WSW_W1T 9216
#define WSW_BT  11776
#define WSW_TOTAL 16000

// 64-lane sum via DPP (VALU pipe, no DS): row_shr 1/2/4/8, bcast15, bcast31.
__device__ inline float wave_reduce_dpp(float v) {
    int x;
    x = __builtin_amdgcn_update_dpp(0, __float_as_int(v), 0x111, 0xf, 0xf, true); v += __int_as_float(x);
    x = __builtin_amdgcn_update_dpp(0, __float_as_int(v), 0x112, 0xf, 0xf, true); v += __int_as_float(x);
    x = __builtin_amdgcn_update_dpp(0, __float_as_int(v), 0x114, 0xf, 0xf, true); v += __int_as_float(x);
    x = __builtin_amdgcn_update_dpp(0, __float_as_int(v), 0x118, 0xf, 0xf, true); v += __int_as_float(x);
    x = __builtin_amdgcn_update_dpp(0, __float_as_int(v), 0x142, 0xa, 0xf, true); v += __int_as_float(x);
    x = __builtin_amdgcn_update_dpp(0, __float_as_int(v), 0x143, 0xc, 0xf, true); v += __int_as_float(x);
    return __int_as_float(__builtin_amdgcn_readlane(__float_as_int(v), 63));
}

// ---------------------------------------------------------------------------
// Kernel A (fused): [0,NPRE) per-node precompute; [NPRE,NPRE+NHIST) histogram;
// last block builds the fp16 weight images (W2T/W1T/BT) in ws.
// ---------------------------------------------------------------------------
__global__ __launch_bounds__(256) void pre_hist_kernel(
    const float* __restrict__ node_input, const float* __restrict__ node_attr,
    const float* __restrict__ w_sc0, const float* __restrict__ w_sc1,
    const float* __restrict__ w_lin1_0, const float* __restrict__ w_lin1_1,
    const float* __restrict__ fc_w1, const float* __restrict__ fc_w2,
    const float* __restrict__ w_se0a, const float* __restrict__ w_se0b,
    const float* __restrict__ w_se1a, const float* __restrict__ w_se1b,
    float* __restrict__ out_self, float* __restrict__ ws_f,
    const int* __restrict__ edge_dst, int* __restrict__ counts,
    _Float16* __restrict__ wsW)
{
    const int t = threadIdx.x;
    if (blockIdx.x == NPRE_BLOCKS + NHIST_BLOCKS) {   // weight-image role
        for (int i = t; i < 8192; i += 256) {          // W2T[c][k], stride 72
            const int c = i >> 6, k = i & 63;
            wsW[WSW_W2T + c * 72 + k] = (_Float16)fc_w2[k * 128 + c];
        }
        for (int i = t; i < 2560; i += 256) {          // W1T[j][k], stride 40
            const int j = i / 40, k = i - j * 40;
            wsW[WSW_W1T + i] = (k < 16) ? (_Float16)fc_w1[k * 64 + j]
                                        : (_Float16)0.f;
        }
        for (int i = t; i < 4224; i += 256) wsW[WSW_BT + i] = (_Float16)0.f;
        __syncthreads();
        {   // BT fill: col 2p <- {se0a|se1b} comp p; col 2p+1 <- {se1a|se0b}
            const int u = t & 63, p = t >> 6;
            const float ev = (p == 0) ? w_se0a[u] : w_se1b[u];
            const float ov = (p == 0) ? w_se1a[u] : w_se0b[u];
            wsW[WSW_BT + (2 * p) * 264 + 4 * u + p]     = (_Float16)ev;
            wsW[WSW_BT + (2 * p + 1) * 264 + 4 * u + p] = (_Float16)ov;
        }
        return;
    }
    if (blockIdx.x >= NPRE_BLOCKS) {          // histogram role
        const int e = (blockIdx.x - NPRE_BLOCKS) * 256 + t;
        if (e < E_EDGES) atomicAdd(&counts[edge_dst[e]], 1);
        return;
    }
    const int n0 = blockIdx.x * 8;
    __shared__ __align__(16) float sx[8 * 128];
    __shared__ float sa[8];
    ((float4*)sx)[t] = ((const float4*)(node_input + (size_t)n0 * 128))[t];
    if (t < 8) sa[t] = node_attr[n0 + t];
    __syncthreads();

    const int half = t >> 7;
    const int idx  = t & 127;
    float wcol[32];
    int m = 0;
    if (idx < 32) {
        const float* __restrict__ W = half ? w_lin1_0 : w_sc0;
        #pragma unroll
        for (int u = 0; u < 32; ++u) wcol[u] = W[u * 32 + idx];
    } else {
        const float* __restrict__ W = half ? w_lin1_1 : w_sc1;
        const int j = idx - 32;
        const int w = j / 3; m = j % 3;
        #pragma unroll
        for (int u = 0; u < 32; ++u) wcol[u] = W[u * 32 + w];
    }
    float* __restrict__ dstp = half ? ws_f : out_self;
    #pragma unroll
    for (int k = 0; k < 8; ++k) {
        const float* x = sx + k * 128;
        float acc = 0.f;
        if (idx < 32) {
            #pragma unroll
            for (int u = 0; u < 32; ++u) acc += x[u] * wcol[u];
        } else {
            #pragma unroll
            for (int u = 0; u < 32; ++u) acc += x[32 + u * 3 + m] * wcol[u];
        }
        dstp[(size_t)(n0 + k) * 128 + idx] = acc * sa[k] * S_IN;
    }
}

// ---------------------------------------------------------------------------
// Sort by dst: block scan -> fixup(with inline 49-prefix) -> scatter
// ---------------------------------------------------------------------------
__global__ __launch_bounds__(1024) void scan_block_kernel(
    const int* __restrict__ counts, int* __restrict__ cursor, int* __restrict__ bsum)
{
    __shared__ int sd[1024];
    const int t   = threadIdx.x;
    const int idx = blockIdx.x * 1024 + t;
    const int c   = (idx < N_NODES) ? counts[idx] : 0;
    sd[t] = c;
    __syncthreads();
    for (int off = 1; off < 1024; off <<= 1) {
        const int v = (t >= off) ? sd[t - off] : 0;
        __syncthreads();
        sd[t] += v;
        __syncthreads();
    }
    if (idx < N_NODES) cursor[idx] = sd[t] - c;   // block-local exclusive
    if (t == 1023) bsum[blockIdx.x] = sd[1023];
}

__global__ __launch_bounds__(1024) void scan_fixup_kernel(
    int* __restrict__ cursor, const int* __restrict__ bsum)
{
    __shared__ int boff_s;
    const int t = threadIdx.x;
    if (t < 64) {                      // prefix of bsum[0..blockIdx-1], one wave
        int v = (t < (int)blockIdx.x) ? bsum[t] : 0;   // blockIdx <= 48 < 64
        #pragma unroll
        for (int off = 32; off >= 1; off >>= 1) v += __shfl_down(v, off, 64);
        if (t == 0) boff_s = v;
    }
    __syncthreads();
    const int idx = blockIdx.x * 1024 + t;
    if (idx < N_NODES) cursor[idx] += boff_s;
}

__global__ __launch_bounds__(256) void scatter_kernel(
    const int* __restrict__ edge_dst, int* __restrict__ cursor,
    int* __restrict__ sorted_eid)
{
    const int e = blockIdx.x * 256 + threadIdx.x;
    if (e < E_EDGES) {
        const int p = atomicAdd(&cursor[edge_dst[e]], 1);
        sorted_eid[p] = e;
    }
}

// ---------------------------------------------------------------------------
// Kernel B: per-edge, dst-sorted, 64 edges/block, 4 waves.
// Weights staged via contiguous f16x8 copies from the precomputed ws image
// (no per-block transpose -> no 16-way staging conflicts). All gathers for a
// wave's 16 edges prefetched before the batch loop.
// Phase1 arena (halfs): W2T[128][72]@0 | HT[64][72]@9216 | ES[64][40]@13824
//                       | W1T[64][40]@16384  (18944 total)
// Phase2 overlay: Wt[64][136]@0 | midA 4wv x 4x272 @8704 | BT[16][264]@13056
// ---------------------------------------------------------------------------
__global__ __launch_bounds__(256, 4) void edge_kernel(
    const float* __restrict__ ws_f,
    const int* __restrict__ edge_src, const int* __restrict__ edge_dst,
    const float* __restrict__ edge_attr, const float* __restrict__ edge_scalars,
    const _Float16* __restrict__ wsW,
    const int* __restrict__ sorted_eid,
    float* __restrict__ nacc, float* __restrict__ edge_out)
{
    __shared__ __align__(16) _Float16 sArena[18944];
    __shared__ __align__(16) float sEA[64 * 4];
    __shared__ __align__(16) float sDep[4][36];     // per-wave 8 cols x 4 edges
    __shared__ int sSRC[64];
    __shared__ int sDST[64];
    __shared__ int sEID[64];

    _Float16* __restrict__ sW2T  = sArena;           // [c][k] stride 72
    _Float16* __restrict__ sHT   = sArena + 9216;    // [e][k] stride 72
    _Float16* __restrict__ sES   = sArena + 13824;   // [e][k] stride 40
    _Float16* __restrict__ sW1T  = sArena + 16384;   // [j][k] stride 40
    _Float16* __restrict__ sWt   = sArena;           // ph2: [e][c] stride 136
    _Float16* __restrict__ sMidA = sArena + 8704;    // ph2: wv*1088 + row*272
    _Float16* __restrict__ sBT   = sArena + 13056;   // ph2: [c][k] stride 264

    const int t    = threadIdx.x;
    const int lane = t & 63;
    const int wv   = t >> 6;
    const int quad = lane >> 4;
    const int mm   = lane & 15;
    const int e0   = blockIdx.x * 64;

    // ---- stage: straight vector copies of precomputed fp16 weight images ----
    {
        const f16x8* __restrict__ gW = (const f16x8*)wsW;
        #pragma unroll
        for (int i = 0; i < 5; ++i) {                 // W2T: 1152 vecs
            const int idx = t + i * 256;
            if (idx < 1152) ((f16x8*)sArena)[idx] = gW[idx];
        }
        #pragma unroll
        for (int i = 0; i < 2; ++i) {                 // W1T: 320 vecs
            const int idx = t + i * 256;
            if (idx < 320) *(f16x8*)&sArena[16384 + idx * 8] = gW[1152 + idx];
        }
    }
    {   // edge_scalars gather -> ES[e][k] fp16, zero-pad k=16..31
        const int e = t >> 2, k4 = (t & 3) * 4;
        const int eid = sorted_eid[e0 + e];
        float4 v = ((const float4*)edge_scalars)[(size_t)eid * 4 + (t & 3)];
        f16x4 p = {(_Float16)v.x, (_Float16)v.y, (_Float16)v.z, (_Float16)v.w};
        *(f16x4*)&sES[e * 40 + k4] = p;
        const f16x4 z4 = {(_Float16)0.f, (_Float16)0.f, (_Float16)0.f, (_Float16)0.f};
        *(f16x4*)&sES[e * 40 + 16 + k4] = z4;
    }
    if (t < 64) {
        const int eid = sorted_eid[e0 + t];
        *(float4*)&sEA[t * 4] = ((const float4*)edge_attr)[eid];
        sEID[t] = eid;
    } else if (t < 128) {
        sSRC[t - 64] = edge_src[sorted_eid[e0 + (t - 64)]];
    } else if (t < 192) {
        sDST[t - 128] = edge_dst[sorted_eid[e0 + (t - 128)]];
    }
    __syncthreads();

    const int eb = wv * 16;

    // ---- fc1 (swapped): D1[j][e] = W1T . ES^T; store h[e][j] via f16x4 ----
    {
        const f16x8 b_es = *(const f16x8*)&sES[(eb + mm) * 40 + quad * 8];
        #pragma unroll
        for (int jt = 0; jt < 4; ++jt) {
            const f16x8 a_w1 = *(const f16x8*)&sW1T[(jt * 16 + mm) * 40 + quad * 8];
            f32x4 d = {0.f, 0.f, 0.f, 0.f};
            d = __builtin_amdgcn_mfma_f32_16x16x32_f16(a_w1, b_es, d, 0, 0, 0);
            f16x4 hv;
            hv[0] = (_Float16)__sinf(d[0] * FC1_S);
            hv[1] = (_Float16)__sinf(d[1] * FC1_S);
            hv[2] = (_Float16)__sinf(d[2] * FC1_S);
            hv[3] = (_Float16)__sinf(d[3] * FC1_S);
            *(f16x4*)&sHT[(eb + mm) * 72 + jt * 16 + quad * 4] = hv;
        }
    }
    __syncthreads();

    // ---- fc2 (swapped): D2[c][e] = W2T . h^T; keep in regs ----
    f32x4 dacc[8];
    {
        const f16x8 b_lo = *(const f16x8*)&sHT[(eb + mm) * 72 + quad * 8];
        const f16x8 b_hi = *(const f16x8*)&sHT[(eb + mm) * 72 + 32 + quad * 8];
        #pragma unroll
        for (int ct = 0; ct < 8; ++ct) {
            const f16x8 a_lo = *(const f16x8*)&sW2T[(ct * 16 + mm) * 72 + quad * 8];
            const f16x8 a_hi = *(const f16x8*)&sW2T[(ct * 16 + mm) * 72 + 32 + quad * 8];
            f32x4 d = {0.f, 0.f, 0.f, 0.f};
            d = __builtin_amdgcn_mfma_f32_16x16x32_f16(a_lo, b_lo, d, 0, 0, 0);
            d = __builtin_amdgcn_mfma_f32_16x16x32_f16(a_hi, b_hi, d, 0, 0, 0);
            dacc[ct] = d;
        }
    }
    __syncthreads();            // all W2T/HT reads done; overlay phase-2

    // Wt[e][c] store (f16x4, c contiguous per lane) + BT copy from ws image
    {
        #pragma unroll
        for (int ct = 0; ct < 8; ++ct) {
            f16x4 v;
            v[0] = (_Float16)(dacc[ct][0] * FC2_S);
            v[1] = (_Float16)(dacc[ct][1] * FC2_S);
            v[2] = (_Float16)(dacc[ct][2] * FC2_S);
            v[3] = (_Float16)(dacc[ct][3] * FC2_S);
            *(f16x4*)&sWt[(eb + mm) * 136 + ct * 16 + quad * 4] = v;
        }
        const _Float16* __restrict__ gBT = wsW + WSW_BT;
        #pragma unroll
        for (int i = 0; i < 3; ++i) {                 // BT: 528 vecs
            const int idx = t + i * 256;
            if (idx < 528) *(f16x8*)&sBT[idx * 8] = *(const f16x8*)&gBT[idx * 8];
        }
    }
    __syncthreads();

    // ---- message phase: prefetch all 48 gathers, then 4 batches ----
    const bool hi = lane >= 32;
    const int  u  = lane - 32;
    const int idxA = hi ? (32 + 3 * u) : lane;
    const int idxB = hi ? (33 + 3 * u) : lane;
    const int idxC = hi ? (34 + 3 * u) : lane;
    const int col1 = hi ? (96 + u) : lane;        // wD[u] | wA[l]
    const int col2 = hi ? (64 + u) : (32 + lane); // wC[u] | wB[l]

    float ga[16], gb[16], gc[16];
    #pragma unroll
    for (int i = 0; i < 16; ++i) {
        const float* fr = ws_f + (size_t)sSRC[eb + i] * 128;
        ga[i] = fr[idxA]; gb[i] = fr[idxB]; gc[i] = fr[idxC];
    }

    int   cur = -1;
    float am0 = 0.f, axx = 0.f, ayy = 0.f, azz = 0.f;
    _Float16* __restrict__ myA = sMidA + wv * 1088;
    const _Float16* __restrict__ arow = myA + (mm & 3) * 272;
    const _Float16* __restrict__ brow = sBT + mm * 264;

    for (int b = 0; b < 4; ++b) {
        #pragma unroll
        for (int i = 0; i < 4; ++i) {
            const int e4  = b * 4 + i;
            const int el  = eb + e4;
            const int dst = sDST[el];
            const float ea0 = sEA[el * 4 + 0];
            const float e1x = sEA[el * 4 + 1];
            const float e1y = sEA[el * 4 + 2];
            const float e1z = sEA[el * 4 + 3];
            const float w1v = (float)sWt[el * 136 + col1];
            const float w2v = (float)sWt[el * 136 + col2];

            float mid0, m1x, m1y, m1z;
            if (!hi) {                       // lanes 0..31: mA, mB
                mid0 = w1v * ga[e4] * ea0;
                const float wbg = w2v * ga[e4];
                m1x = wbg * e1x; m1y = wbg * e1y; m1z = wbg * e1z;
            } else {                         // lanes 32..63: mD, mC
                const float dot = ga[e4] * e1x + gb[e4] * e1y + gc[e4] * e1z;
                mid0 = w1v * dot * INV_SQRT3;
                const float wce = w2v * ea0;
                m1x = wce * ga[e4]; m1y = wce * gb[e4]; m1z = wce * gc[e4];
            }

            if (dst != cur) {               // segment flush (dst wave-uniform)
                if (cur >= 0) {
                    float* np_ = nacc + (size_t)cur * 256;
                    atomicAdd(np_ + lane, am0);
                    atomicAdd(np_ + 64 + lane * 3 + 0, axx);
                    atomicAdd(np_ + 64 + lane * 3 + 1, ayy);
                    atomicAdd(np_ + 64 + lane * 3 + 2, azz);
                }
                cur = dst; am0 = axx = ayy = azz = 0.f;
            }
            am0 += mid0; axx += m1x; ayy += m1y; azz += m1z;

            // mid -> A-tile row i, k = 4*lane + {0,1,2,3}
            f16x4 mv;
            mv[0] = (_Float16)mid0; mv[1] = (_Float16)m1x;
            mv[2] = (_Float16)m1y;  mv[3] = (_Float16)m1z;
            *(f16x4*)&myA[i * 272 + 4 * lane] = mv;
        }

        // se matmul: [4e x 256k] x [256k x 8c]; two accumulators halve chain
        f32x4 d0 = {0.f, 0.f, 0.f, 0.f};
        f32x4 d1 = {0.f, 0.f, 0.f, 0.f};
        #pragma unroll
        for (int ks = 0; ks < 4; ++ks) {
            const f16x8 a0  = *(const f16x8*)&arow[(2 * ks) * 32 + quad * 8];
            const f16x8 bb0 = *(const f16x8*)&brow[(2 * ks) * 32 + quad * 8];
            const f16x8 a1  = *(const f16x8*)&arow[(2 * ks + 1) * 32 + quad * 8];
            const f16x8 bb1 = *(const f16x8*)&brow[(2 * ks + 1) * 32 + quad * 8];
            d0 = __builtin_amdgcn_mfma_f32_16x16x32_f16(a0, bb0, d0, 0, 0, 0);
            d1 = __builtin_amdgcn_mfma_f32_16x16x32_f16(a1, bb1, d1, 0, 0, 0);
        }
        f32x4 d;
        d[0] = d0[0] + d1[0]; d[1] = d0[1] + d1[1];
        d[2] = d0[2] + d1[2]; d[3] = d0[3] + d1[3];

        if (lane < 8) {                 // quad 0: reg r = edge b*4+r, col = lane
            float4 f4; f4.x = d[0]; f4.y = d[1]; f4.z = d[2]; f4.w = d[3];
            *(float4*)&sDep[wv][lane * 4] = f4;
        }
        if (lane < 4) {                 // lane = edge within batch
            const int el = eb + b * 4 + lane;
            const float c0 = sDep[wv][ 0 + lane], c1 = sDep[wv][ 4 + lane];
            const float c2 = sDep[wv][ 8 + lane], c3 = sDep[wv][12 + lane];
            const float c4 = sDep[wv][16 + lane], c5 = sDep[wv][20 + lane];
            const float c6 = sDep[wv][24 + lane], c7 = sDep[wv][28 + lane];
            const float ea0 = sEA[el * 4 + 0];
            const float e1x = sEA[el * 4 + 1];
            const float e1y = sEA[el * 4 + 2];
            const float e1z = sEA[el * 4 + 3];
            const float s0 = c0 * ea0 + (c3 * e1x + c5 * e1y + c7 * e1z) * INV_SQRT3;
            float4 o;
            o.x = ea0 + s0 * S_SE * INV_NN;
            o.y = e1x + (c1 * e1x + c2 * ea0) * S_SE * INV_NN;
            o.z = e1y + (c1 * e1y + c4 * ea0) * S_SE * INV_NN;
            o.w = e1z + (c1 * e1z + c6 * ea0) * S_SE * INV_NN;
            *(float4*)&edge_out[(size_t)sEID[el] * 4] = o;
        }
    }
    if (cur >= 0) {
        float* np_ = nacc + (size_t)cur * 256;
        atomicAdd(np_ + lane, am0);
        atomicAdd(np_ + 64 + lane * 3 + 0, axx);
        atomicAdd(np_ + 64 + lane * 3 + 1, ayy);
        atomicAdd(np_ + 64 + lane * 3 + 2, azz);
    }
}

// ---------------------------------------------------------------------------
// Kernel C: per-node post; 8 nodes/block, weight column in registers.
// ---------------------------------------------------------------------------
__global__ __launch_bounds__(128) void node_post_kernel(
    const float* __restrict__ nacc, const float* __restrict__ node_attr,
    const float* __restrict__ w_lin2_0, const float* __restrict__ w_lin2_1,
    const float* __restrict__ w_alpha, float* __restrict__ out)
{
    const int n0 = blockIdx.x * 8, t = threadIdx.x;
    __shared__ __align__(16) float sn[8 * 256];
    __shared__ float salpha[8];
    const float4* src = (const float4*)(nacc + (size_t)n0 * 256);
    #pragma unroll
    for (int i = 0; i < 4; ++i) ((float4*)sn)[t + i * 128] = src[t + i * 128];
    __syncthreads();

    if (t < 64) {
        const float wa = w_alpha[t];
        #pragma unroll
        for (int k = 0; k < 8; ++k) {
            const float r = wave_reduce_dpp(sn[k * 256 + t] * wa);
            if (t == 0) salpha[k] = r;
        }
    }
    __syncthreads();

    float wcol[64];
    int m = 0;
    if (t < 32) {
        #pragma unroll
        for (int u = 0; u < 64; ++u) wcol[u] = w_lin2_0[u * 32 + t];
    } else {
        const int j = t - 32; const int w = j / 3; m = j % 3;
        #pragma unroll
        for (int u = 0; u < 64; ++u) wcol[u] = w_lin2_1[u * 32 + w];
    }
    #pragma unroll
    for (int k = 0; k < 8; ++k) {
        const float* s = sn + k * 256;
        float acc = 0.f;
        if (t < 32) {
            #pragma unroll
            for (int u = 0; u < 64; ++u) acc += s[u] * wcol[u];
        } else {
            #pragma unroll
            for (int u = 0; u < 64; ++u) acc += s[64 + u * 3 + m] * wcol[u];
        }
        const float a  = node_attr[n0 + k];
        const float sc = a * S_MID * INV_NN;
        const size_t o = (size_t)(n0 + k) * 128 + t;
        out[o] = out[o] + (salpha[k] * sc) * (acc * sc);
    }
}

extern "C" void kernel_launch(void* const* d_in, const int* in_sizes, int n_in,
                              void* d_out, int out_size, void* d_ws, size_t ws_size,
                              hipStream_t stream)
{
    const float* node_input   = (const float*)d_in[0];
    const float* node_attr    = (const float*)d_in[1];
    const int*   edge_src     = (const int*)d_in[2];
    const int*   edge_dst     = (const int*)d_in[3];
    const float* edge_attr    = (const float*)d_in[4];
    const float* edge_scalars = (const float*)d_in[5];
    const float* w_sc0        = (const float*)d_in[6];
    const float* w_sc1        = (const float*)d_in[7];
    const float* w_lin1_0     = (const float*)d_in[8];
    const float* w_lin1_1     = (const float*)d_in[9];
    const float* fc_w1        = (const float*)d_in[10];
    const float* fc_w2        = (const float*)d_in[11];
    const float* w_lin2_0     = (const float*)d_in[12];
    const float* w_lin2_1     = (const float*)d_in[13];
    const float* w_alpha      = (const float*)d_in[14];
    const float* w_se0a       = (const float*)d_in[15];
    const float* w_se0b       = (const float*)d_in[16];
    const float* w_se1a       = (const float*)d_in[17];
    const float* w_se1b       = (const float*)d_in[18];

    float* out      = (float*)d_out;
    float* edge_out = out + (size_t)N_NODES * 128;

    float* ws_f   = (float*)d_ws;                          // N*128 f
    float* nacc   = ws_f + (size_t)N_NODES * 128;          // N*256 f
    int*   counts = (int*)(nacc + (size_t)N_NODES * 256);  // N
    int*   cursor = counts + N_NODES;                      // N
    int*   sid    = cursor + N_NODES;                      // E
    int*   bsum   = sid + E_EDGES;                         // 64
    uintptr_t wp  = ((uintptr_t)(bsum + 64) + 15) & ~(uintptr_t)15;
    _Float16* wsW = (_Float16*)wp;                         // 16000 halfs

    hipMemsetAsync(nacc, 0,
        ((size_t)N_NODES * 256 + N_NODES) * sizeof(float), stream);  // nacc+counts

    pre_hist_kernel<<<NPRE_BLOCKS + NHIST_BLOCKS + 1, 256, 0, stream>>>(
        node_input, node_attr, w_sc0, w_sc1, w_lin1_0, w_lin1_1,
        fc_w1, fc_w2, w_se0a, w_se0b, w_se1a, w_se1b,
        out, ws_f, edge_dst, counts, wsW);

    scan_block_kernel<<<49, 1024, 0, stream>>>(counts, cursor, bsum);
    scan_fixup_kernel<<<49, 1024, 0, stream>>>(cursor, bsum);
    scatter_kernel<<<(E_EDGES + 255) / 256, 256, 0, stream>>>(edge_dst, cursor, sid);

    edge_kernel<<<E_EDGES / 64, 256, 0, stream>>>(
        ws_f, edge_src, edge_dst, edge_attr, edge_scalars, wsW,
        sid, nacc, edge_out);

    node_post_kernel<<<N_NODES / 8, 128, 0, stream>>>(
        nacc, node_attr, w_lin2_0, w_lin2_1, w_alpha, out);
}